// Round 1
// baseline (106.072 us; speedup 1.0000x reference)
//
#include <hip/hip_runtime.h>
#include <math.h>

// Problem constants (from reference setup_inputs)
#define B_     256
#define V_     50
#define C_     32
#define E_     128
#define VOCAB_ 100000
#define L_     (V_ * C_)      // 1600 flattened codes per patient
#define SPB    8              // blocks per patient (R7 best)
#define NCHUNK (SPB * 4)      // bag wave-chunks per patient (32) -> chunk <= 50
#define NBLK   (B_ * SPB)     // 2048 blocks

#define NROWS_PER_BLK 16
#define NORM_BLKS (VOCAB_ / NROWS_PER_BLK)   // 6250 (exact: 6250*16 = 100000)
#define PART_OFF_BYTES (1 << 19)             // part[] at +512 KiB (past 400 KB nscale)

// R13: hoist the renorm out of the gather loop.
// Evidence: FETCH_SIZE=47MB == unique-row working set -> the harness's 256MB
// d_ws re-poison evicts W from L3 every iteration; at 55MB HBM traffic the
// byte-roofline is ~9us but we sit at ~98us and bf16 (R9) changed nothing ->
// latency/critical-path bound, not bytes. The per-row chain
// (load -> vmcnt(0) -> ss -> 4 dependent shfl_xor -> sqrt -> rcp -> fma)
// serializes ~209k gathers. nscale[code] is a pure function of W, so:
//   kernel 1: streaming prepass computes nscale[100000] (51MB seq read,
//             ~8-10us) AND re-warms L3 with the whole table.
//   kernel 2: gather loop is now shfl(code)+shfl(scale) -> 2 loads -> 8 FMA.
//             No cross-lane reduce, no transcendentals, pure MLP.

__global__ __launch_bounds__(256) void norm_kernel(
    const float* __restrict__ W,       // [VOCAB, E]
    float*       __restrict__ nscale)  // [VOCAB]
{
    const int tid  = threadIdx.x;
    const int wave = tid >> 6;
    const int lane = tid & 63;
    const int g    = lane >> 4;
    const int l4   = lane & 15;
    const int row  = blockIdx.x * NROWS_PER_BLK + wave * 4 + g;  // always < VOCAB_
    const float4* r = (const float4*)(W + (size_t)row * E_);
    float4 v1 = r[l4];
    float4 v2 = r[16 + l4];
    float ss = v1.x*v1.x + v1.y*v1.y + v1.z*v1.z + v1.w*v1.w
             + v2.x*v2.x + v2.y*v2.y + v2.z*v2.z + v2.w*v2.w;
    #pragma unroll
    for (int m = 1; m <= 8; m <<= 1) ss += __shfl_xor(ss, m, 64);
    if (l4 == 0)
        nscale[row] = fminf(1.0f, 1.0f / fmaxf(sqrtf(ss), 1e-12f));
}

__global__ __launch_bounds__(256, 6) void fused_kernel(
    const float* __restrict__ W,       // [VOCAB, E]
    const int*   __restrict__ codes,   // [B, V, C]
    const int*   __restrict__ nvis,    // [B]
    const float* __restrict__ nscale,  // [VOCAB] precomputed renorm scales
    float*       __restrict__ out,     // [B, V, E]
    float*       __restrict__ part)    // [B_, SPB, E] partials in d_ws
{
    const int tid  = threadIdx.x;
    const int wave = tid >> 6;
    const int lane = tid & 63;
    const int g    = lane >> 4;       // row group within wave [0,4)
    const int l4   = lane & 15;       // lane within group

    const int b  = blockIdx.x >> 3;        // / SPB
    const int s  = blockIdx.x & (SPB - 1);
    const int nv = nvis[b];
    const int* cf = codes + b * L_;
    float* ob = out + (size_t)b * V_ * E_;

    // ---- bag geometry; issue the per-wave code fetch EARLY so its latency
    //      hides under the singles phase ----
    const int j0    = nv - 1;
    const int j1    = nv * C_;
    const int chunk = (j1 - j0 + NCHUNK - 1) / NCHUNK;   // <= 50
    const int wid   = s * 4 + wave;                      // [0, 32)
    const int a0    = j0 + wid * chunk;
    const int n     = min(a0 + chunk, j1) - a0;          // may be <= 0
    int cl = 0;
    if (lane < n) cl = cf[a0 + lane];                    // batched code fetch

    // ---- singles + pads: one output row per (wave,group); i = k*8+s ----
    {
        const int i = (wave * 4 + g) * SPB + s;    // unique cover of [0,128)
        if (i < V_ - 1) {
            if (i < nv - 1) {
                const int code = cf[i];
                const float* row = W + (size_t)code * E_;
                float4 v1 = ((const float4*)row)[l4];
                float4 v2 = ((const float4*)row)[16 + l4];
                const float sc = nscale[code];     // broadcast (same addr x16)
                float* orow = ob + (size_t)(V_ - nv + i) * E_;
                ((float4*)orow)[l4]      = make_float4(v1.x*sc, v1.y*sc, v1.z*sc, v1.w*sc);
                ((float4*)orow)[16 + l4] = make_float4(v2.x*sc, v2.y*sc, v2.z*sc, v2.w*sc);
            } else {
                float* orow = ob + (size_t)(i - (nv - 1)) * E_;
                ((float4*)orow)[l4]      = make_float4(0.f, 0.f, 0.f, 0.f);
                ((float4*)orow)[16 + l4] = make_float4(0.f, 0.f, 0.f, 0.f);
            }
        }
    }

    // per-lane scale fetch (tiny 400KB L2-resident table); lanes >= n hold 0
    float sl = 0.0f;
    if (lane < n) sl = nscale[cl];

    // ---- bag partial sum: wave chunk of <= 50 codes, 4 rows per iter.
    //      Per iteration: 2 shuffles -> 2 loads -> 8 FMA. No reduce. ----
    float4 a1 = make_float4(0.f, 0.f, 0.f, 0.f);
    float4 a2 = make_float4(0.f, 0.f, 0.f, 0.f);
    #pragma unroll 4
    for (int t = 0; t < n; t += 4) {
        const int tt   = t + g;                  // group g -> row t+g
        const int code = __shfl(cl, tt, 64);     // tt>=n -> cl=0 (row 0, sc=0)
        float sc       = __shfl(sl, tt, 64);     // tt>=n lanes hold sl=0
        if (tt >= n) sc = 0.0f;                  // belt-and-braces mask
        const float* row = W + (size_t)code * E_;
        float4 v1 = ((const float4*)row)[l4];
        float4 v2 = ((const float4*)row)[16 + l4];
        a1.x += v1.x*sc; a1.y += v1.y*sc; a1.z += v1.z*sc; a1.w += v1.w*sc;
        a2.x += v2.x*sc; a2.y += v2.y*sc; a2.z += v2.z*sc; a2.w += v2.w*sc;
    }

    // combine the 4 groups (same col mapping in every group)
    #pragma unroll
    for (int m = 16; m <= 32; m <<= 1) {
        a1.x += __shfl_xor(a1.x, m, 64); a1.y += __shfl_xor(a1.y, m, 64);
        a1.z += __shfl_xor(a1.z, m, 64); a1.w += __shfl_xor(a1.w, m, 64);
        a2.x += __shfl_xor(a2.x, m, 64); a2.y += __shfl_xor(a2.y, m, 64);
        a2.z += __shfl_xor(a2.z, m, 64); a2.w += __shfl_xor(a2.w, m, 64);
    }

    __shared__ float4 s1[4][16], s2[4][16];
    if (lane < 16) { s1[wave][l4] = a1; s2[wave][l4] = a2; }
    __syncthreads();
    // plain coalesced partial store: 32 lanes x float4 = 512B, NO atomics
    if (tid < 32) {
        const int h = tid >> 4;          // 0: cols [0,64), 1: cols [64,128)
        const int q = tid & 15;
        float4 f = (h == 0) ? s1[0][q] : s2[0][q];
        #pragma unroll
        for (int w = 1; w < 4; w++) {
            float4 p = (h == 0) ? s1[w][q] : s2[w][q];
            f.x += p.x; f.y += p.y; f.z += p.z; f.w += p.w;
        }
        ((float4*)(part + (size_t)blockIdx.x * E_))[tid] = f;
    }
}

// Reduce: one block per patient, 128 threads; thread t sums partials over
// s (reads coalesced across threads) and writes bag-row element t.
__global__ __launch_bounds__(128) void reduce_kernel(
    const float* __restrict__ part,   // [B_, SPB, E]
    float*       __restrict__ out)    // [B, V, E]
{
    const int b = blockIdx.x;
    const int t = threadIdx.x;
    const float* p = part + (size_t)b * SPB * E_;
    float acc = 0.0f;
    #pragma unroll
    for (int s = 0; s < SPB; s++) acc += p[s * E_ + t];
    out[((size_t)b * V_ + (V_ - 1)) * E_ + t] = acc;
}

extern "C" void kernel_launch(void* const* d_in, const int* in_sizes, int n_in,
                              void* d_out, int out_size, void* d_ws, size_t ws_size,
                              hipStream_t stream) {
    const float* W     = (const float*)d_in[0];
    const int*   codes = (const int*)d_in[1];
    const int*   nvis  = (const int*)d_in[2];
    float*       out   = (float*)d_out;
    float*       nscale = (float*)d_ws;                          // 400 KB
    float*       part   = (float*)((char*)d_ws + PART_OFF_BYTES); // 1 MB

    norm_kernel<<<NORM_BLKS, 256, 0, stream>>>(W, nscale);
    fused_kernel<<<NBLK, 256, 0, stream>>>(W, codes, nvis, nscale, out, part);
    reduce_kernel<<<B_, 128, 0, stream>>>(part, out);
}

// Round 2
// 97.571 us; speedup vs baseline: 1.0871x; 1.0871x over previous
//
#include <hip/hip_runtime.h>
#include <math.h>

// Problem constants (from reference setup_inputs)
#define B_     256
#define V_     50
#define C_     32
#define E_     128
#define VOCAB_ 100000
#define L_     (V_ * C_)      // 1600 flattened codes per patient
#define SPB    8              // blocks per patient (R7 best)
#define NCHUNK (SPB * 4)      // bag wave-chunks per patient (32) -> chunk <= 49
#define NBLK   (B_ * SPB)     // 2048 blocks

// R14: attack per-wave MLP, revert the norm prepass.
// R13 post-mortem: removing the whole norm chain (prepass) changed fused
// time by ~0 and cost +8us -> gather is NOT VALU-chain bound, NOT byte
// bound (R9 bf16 null). VGPR_Count=24 proves the compiler serialized the
// bag loop (8 in-flight float4 need 32 VGPRs alone): each wave runs ~13
// dependent load->drain->reduce convoys ~7us serial. Also: the timed
// region contains a fixed ~42us 256MiB d_ws poison fill (WRITE_SIZE==
// ws_size) that thrashes L3 -> iteration starts cold; budget we control
// is fused(~40)+reduce(~5).
// Fix: explicit depth-2 software pipeline, 8 rows/step, NAMED batch regs
// (no runtime-indexed arrays -> no scratch). Inline norm overlaps the
// next step's loads. launch_bounds(256,4) gives the allocator headroom.

__device__ __forceinline__ float dot8(const float4 v1, const float4 v2) {
    return v1.x*v1.x + v1.y*v1.y + v1.z*v1.z + v1.w*v1.w
         + v2.x*v2.x + v2.y*v2.y + v2.z*v2.z + v2.w*v2.w;
}

__global__ __launch_bounds__(256, 4) void fused_kernel(
    const float* __restrict__ W,      // [VOCAB, E]
    const int*   __restrict__ codes,  // [B, V, C]
    const int*   __restrict__ nvis,   // [B]
    float*       __restrict__ out,    // [B, V, E]
    float*       __restrict__ part)   // [B_, SPB, E] partials in d_ws
{
    const int tid  = threadIdx.x;
    const int wave = tid >> 6;
    const int lane = tid & 63;
    const int g    = lane >> 4;       // row group within wave [0,4)
    const int l4   = lane & 15;       // lane within group

    const int b  = blockIdx.x >> 3;        // / SPB
    const int s  = blockIdx.x & (SPB - 1);
    const int nv = nvis[b];
    const int* cf = codes + b * L_;
    float* ob = out + (size_t)b * V_ * E_;

    // ---- bag geometry; batched per-wave code fetch issued EARLY ----
    const int j0    = nv - 1;
    const int j1    = nv * C_;
    const int chunk = (j1 - j0 + NCHUNK - 1) / NCHUNK;   // <= 49
    const int wid   = s * 4 + wave;                      // [0, 32)
    const int a0    = j0 + wid * chunk;
    const int n     = min(a0 + chunk, j1) - a0;          // may be <= 0
    int cl = 0;
    if (lane < n) cl = cf[a0 + lane];                    // codes for this chunk

    // ---- singles + pads: one output row per (wave,group); i = k*8+s ----
    {
        const int i = (wave * 4 + g) * SPB + s;    // unique cover of [0,128)
        if (i < V_ - 1) {
            if (i < nv - 1) {
                const int code = cf[i];
                const float* row = W + (size_t)code * E_;
                float4 v1 = ((const float4*)row)[l4];
                float4 v2 = ((const float4*)row)[16 + l4];
                float ss = dot8(v1, v2);
                #pragma unroll
                for (int m = 1; m <= 8; m <<= 1) ss += __shfl_xor(ss, m, 64);
                const float sc = fminf(1.0f, 1.0f / fmaxf(sqrtf(ss), 1e-12f));
                float* orow = ob + (size_t)(V_ - nv + i) * E_;
                ((float4*)orow)[l4]      = make_float4(v1.x*sc, v1.y*sc, v1.z*sc, v1.w*sc);
                ((float4*)orow)[16 + l4] = make_float4(v2.x*sc, v2.y*sc, v2.z*sc, v2.w*sc);
            } else {
                float* orow = ob + (size_t)(i - (nv - 1)) * E_;
                ((float4*)orow)[l4]      = make_float4(0.f, 0.f, 0.f, 0.f);
                ((float4*)orow)[16 + l4] = make_float4(0.f, 0.f, 0.f, 0.f);
            }
        }
    }

    // ---- bag partial sum: depth-2 pipeline, 8 rows per step.
    //      Step t: group g owns rows t+g (batch A) and t+4+g (batch B).
    //      While PROC(t) runs its norm chain, ISSUE(t+8)'s 4 float4 loads
    //      are in flight -> ~8 float4 outstanding per lane. ----
    float4 a1 = make_float4(0.f, 0.f, 0.f, 0.f);
    float4 a2 = make_float4(0.f, 0.f, 0.f, 0.f);

#define ISSUE(T, XV1, XV2, YV1, YV2) do {                                   \
        const int cA = __shfl(cl, (T) + g, 64);                             \
        const int cB = __shfl(cl, (T) + 4 + g, 64);                         \
        const float4* rA = (const float4*)(W + (size_t)cA * E_);            \
        const float4* rB = (const float4*)(W + (size_t)cB * E_);            \
        XV1 = rA[l4]; XV2 = rA[16 + l4];                                    \
        YV1 = rB[l4]; YV2 = rB[16 + l4];                                    \
    } while (0)

#define PROC(T, XV1, XV2, YV1, YV2) do {                                    \
        float ssA = dot8(XV1, XV2);                                         \
        float ssB = dot8(YV1, YV2);                                         \
        _Pragma("unroll")                                                   \
        for (int m = 1; m <= 8; m <<= 1) {                                  \
            ssA += __shfl_xor(ssA, m, 64);                                  \
            ssB += __shfl_xor(ssB, m, 64);                                  \
        }                                                                   \
        float scA = fminf(1.0f, 1.0f / fmaxf(sqrtf(ssA), 1e-12f));          \
        float scB = fminf(1.0f, 1.0f / fmaxf(sqrtf(ssB), 1e-12f));          \
        if ((T) + g     >= n) scA = 0.0f;                                   \
        if ((T) + 4 + g >= n) scB = 0.0f;                                   \
        a1.x += XV1.x*scA + YV1.x*scB; a1.y += XV1.y*scA + YV1.y*scB;       \
        a1.z += XV1.z*scA + YV1.z*scB; a1.w += XV1.w*scA + YV1.w*scB;       \
        a2.x += XV2.x*scA + YV2.x*scB; a2.y += XV2.y*scA + YV2.y*scB;       \
        a2.z += XV2.z*scA + YV2.z*scB; a2.w += XV2.w*scA + YV2.w*scB;       \
    } while (0)

    if (n > 0) {
        float4 Av1, Av2, Bv1, Bv2;        // current step (named: rule #20)
        float4 Cv1, Cv2, Dv1, Dv2;        // next step
        ISSUE(0, Av1, Av2, Bv1, Bv2);
        int t = 0;
        for (; t + 8 < n; t += 8) {
            ISSUE(t + 8, Cv1, Cv2, Dv1, Dv2);   // loads in flight...
            PROC(t, Av1, Av2, Bv1, Bv2);        // ...while norm chain runs
            Av1 = Cv1; Av2 = Cv2; Bv1 = Dv1; Bv2 = Dv2;
        }
        PROC(t, Av1, Av2, Bv1, Bv2);            // tail (masked)
    }
#undef ISSUE
#undef PROC

    // combine the 4 groups (same col mapping in every group)
    #pragma unroll
    for (int m = 16; m <= 32; m <<= 1) {
        a1.x += __shfl_xor(a1.x, m, 64); a1.y += __shfl_xor(a1.y, m, 64);
        a1.z += __shfl_xor(a1.z, m, 64); a1.w += __shfl_xor(a1.w, m, 64);
        a2.x += __shfl_xor(a2.x, m, 64); a2.y += __shfl_xor(a2.y, m, 64);
        a2.z += __shfl_xor(a2.z, m, 64); a2.w += __shfl_xor(a2.w, m, 64);
    }

    __shared__ float4 s1[4][16], s2[4][16];
    if (lane < 16) { s1[wave][l4] = a1; s2[wave][l4] = a2; }
    __syncthreads();
    // plain coalesced partial store: 32 lanes x float4 = 512B, NO atomics
    if (tid < 32) {
        const int h = tid >> 4;          // 0: cols [0,64), 1: cols [64,128)
        const int q = tid & 15;
        float4 f = (h == 0) ? s1[0][q] : s2[0][q];
        #pragma unroll
        for (int w = 1; w < 4; w++) {
            float4 p = (h == 0) ? s1[w][q] : s2[w][q];
            f.x += p.x; f.y += p.y; f.z += p.z; f.w += p.w;
        }
        ((float4*)(part + (size_t)blockIdx.x * E_))[tid] = f;
    }
}

// Reduce: one block per patient, 128 threads; thread t sums partials over
// s (reads coalesced across threads) and writes bag-row element t.
__global__ __launch_bounds__(128) void reduce_kernel(
    const float* __restrict__ part,   // [B_, SPB, E]
    float*       __restrict__ out)    // [B, V, E]
{
    const int b = blockIdx.x;
    const int t = threadIdx.x;
    const float* p = part + (size_t)b * SPB * E_;
    float acc = 0.0f;
    #pragma unroll
    for (int s = 0; s < SPB; s++) acc += p[s * E_ + t];
    out[((size_t)b * V_ + (V_ - 1)) * E_ + t] = acc;
}

extern "C" void kernel_launch(void* const* d_in, const int* in_sizes, int n_in,
                              void* d_out, int out_size, void* d_ws, size_t ws_size,
                              hipStream_t stream) {
    const float* W     = (const float*)d_in[0];
    const int*   codes = (const int*)d_in[1];
    const int*   nvis  = (const int*)d_in[2];
    float*       out   = (float*)d_out;
    float*       part  = (float*)d_ws;   // B_*SPB*E_*4 = 1 MB scratch

    fused_kernel<<<NBLK, 256, 0, stream>>>(W, codes, nvis, out, part);
    reduce_kernel<<<B_, 128, 0, stream>>>(part, out);
}

// Round 3
// 97.425 us; speedup vs baseline: 1.0888x; 1.0015x over previous
//
#include <hip/hip_runtime.h>
#include <math.h>

// Problem constants (from reference setup_inputs)
#define B_     256
#define V_     50
#define C_     32
#define E_     128
#define VOCAB_ 100000
#define L_     (V_ * C_)      // 1600 flattened codes per patient
#define NW     16             // waves per block
#define THREADS (NW * 64)     // 1024

// R15: single-dispatch merge. R14 post-mortem: 4x MLP null, bytes null
// (R9), VALU-chain null (R13) -> fused is already near its ~10us random
// fetch floor; total is dominated by harness reset traffic (Dispatch_Id
// spacing shows ~40 dispatches/iter: one 42.5us 256MiB poison fill +
// dozens of tiny restores). Only controllable slack left: our own
// dispatch count + the reduce kernel. This round: ONE block per patient
// (256 x 1024 threads, 16 waves), codes staged to LDS, bag partial
// reduction done in LDS -> no partials buffer, no reduce_kernel, no
// d_ws use at all. Keeps the R14 depth-2 pipeline verbatim.

__device__ __forceinline__ float dot8(const float4 v1, const float4 v2) {
    return v1.x*v1.x + v1.y*v1.y + v1.z*v1.z + v1.w*v1.w
         + v2.x*v2.x + v2.y*v2.y + v2.z*v2.z + v2.w*v2.w;
}

__global__ __launch_bounds__(THREADS, 4) void fused_kernel(
    const float* __restrict__ W,      // [VOCAB, E]
    const int*   __restrict__ codes,  // [B, V, C]
    const int*   __restrict__ nvis,   // [B]
    float*       __restrict__ out)    // [B, V, E]
{
    __shared__ int    scode[L_ + 16];   // staged codes (+pad for pipeline)
    __shared__ float4 s1[NW][16], s2[NW][16];

    const int tid  = threadIdx.x;
    const int wave = tid >> 6;        // [0,16)
    const int lane = tid & 63;
    const int g    = lane >> 4;       // row group within wave [0,4)
    const int l4   = lane & 15;       // lane within group

    const int b  = blockIdx.x;        // one block per patient
    const int nv = nvis[b];
    const int* cf = codes + b * L_;
    float* ob = out + (size_t)b * V_ * E_;

    const int j0 = nv - 1;
    const int j1 = nv * C_;           // <= 1600

    // ---- stage this patient's codes into LDS (coalesced, 2 rounds) ----
    for (int k = tid; k < j1; k += THREADS) scode[k] = cf[k];
    if (tid < 16) scode[j1 + tid] = 0;   // pad: pipeline overreads <= +7
    __syncthreads();

    // ---- singles + pads: one output row per (wave,group), i in [0,64) ----
    {
        const int i = wave * 4 + g;
        if (i < V_ - 1) {
            if (i < nv - 1) {
                const int code = scode[i];
                const float* row = W + (size_t)code * E_;
                float4 v1 = ((const float4*)row)[l4];
                float4 v2 = ((const float4*)row)[16 + l4];
                float ss = dot8(v1, v2);
                #pragma unroll
                for (int m = 1; m <= 8; m <<= 1) ss += __shfl_xor(ss, m, 64);
                const float sc = fminf(1.0f, 1.0f / fmaxf(sqrtf(ss), 1e-12f));
                float* orow = ob + (size_t)(V_ - nv + i) * E_;
                ((float4*)orow)[l4]      = make_float4(v1.x*sc, v1.y*sc, v1.z*sc, v1.w*sc);
                ((float4*)orow)[16 + l4] = make_float4(v2.x*sc, v2.y*sc, v2.z*sc, v2.w*sc);
            } else {
                float* orow = ob + (size_t)(i - (nv - 1)) * E_;
                ((float4*)orow)[l4]      = make_float4(0.f, 0.f, 0.f, 0.f);
                ((float4*)orow)[16 + l4] = make_float4(0.f, 0.f, 0.f, 0.f);
            }
        }
    }

    // ---- bag partial sum: wave chunk <= 97 codes, depth-2 pipeline,
    //      8 rows/step, codes broadcast-read from LDS ----
    const int chunk = (j1 - j0 + NW - 1) / NW;
    const int a0    = j0 + wave * chunk;
    const int n     = min(a0 + chunk, j1) - a0;   // may be <= 0

    float4 a1 = make_float4(0.f, 0.f, 0.f, 0.f);
    float4 a2 = make_float4(0.f, 0.f, 0.f, 0.f);

#define ISSUE(T, XV1, XV2, YV1, YV2) do {                                   \
        const int cA = scode[a0 + (T) + g];                                 \
        const int cB = scode[a0 + (T) + 4 + g];                             \
        const float4* rA = (const float4*)(W + (size_t)cA * E_);            \
        const float4* rB = (const float4*)(W + (size_t)cB * E_);            \
        XV1 = rA[l4]; XV2 = rA[16 + l4];                                    \
        YV1 = rB[l4]; YV2 = rB[16 + l4];                                    \
    } while (0)

#define PROC(T, XV1, XV2, YV1, YV2) do {                                    \
        float ssA = dot8(XV1, XV2);                                         \
        float ssB = dot8(YV1, YV2);                                         \
        _Pragma("unroll")                                                   \
        for (int m = 1; m <= 8; m <<= 1) {                                  \
            ssA += __shfl_xor(ssA, m, 64);                                  \
            ssB += __shfl_xor(ssB, m, 64);                                  \
        }                                                                   \
        float scA = fminf(1.0f, 1.0f / fmaxf(sqrtf(ssA), 1e-12f));          \
        float scB = fminf(1.0f, 1.0f / fmaxf(sqrtf(ssB), 1e-12f));          \
        if ((T) + g     >= n) scA = 0.0f;                                   \
        if ((T) + 4 + g >= n) scB = 0.0f;                                   \
        a1.x += XV1.x*scA + YV1.x*scB; a1.y += XV1.y*scA + YV1.y*scB;       \
        a1.z += XV1.z*scA + YV1.z*scB; a1.w += XV1.w*scA + YV1.w*scB;       \
        a2.x += XV2.x*scA + YV2.x*scB; a2.y += XV2.y*scA + YV2.y*scB;       \
        a2.z += XV2.z*scA + YV2.z*scB; a2.w += XV2.w*scA + YV2.w*scB;       \
    } while (0)

    if (n > 0) {
        float4 Av1, Av2, Bv1, Bv2;        // current step (named: rule #20)
        float4 Cv1, Cv2, Dv1, Dv2;        // next step
        ISSUE(0, Av1, Av2, Bv1, Bv2);
        int t = 0;
        for (; t + 8 < n; t += 8) {
            ISSUE(t + 8, Cv1, Cv2, Dv1, Dv2);   // loads in flight...
            PROC(t, Av1, Av2, Bv1, Bv2);        // ...while norm chain runs
            Av1 = Cv1; Av2 = Cv2; Bv1 = Dv1; Bv2 = Dv2;
        }
        PROC(t, Av1, Av2, Bv1, Bv2);            // tail (masked)
    }
#undef ISSUE
#undef PROC

    // combine the 4 groups (same col mapping in every group)
    #pragma unroll
    for (int m = 16; m <= 32; m <<= 1) {
        a1.x += __shfl_xor(a1.x, m, 64); a1.y += __shfl_xor(a1.y, m, 64);
        a1.z += __shfl_xor(a1.z, m, 64); a1.w += __shfl_xor(a1.w, m, 64);
        a2.x += __shfl_xor(a2.x, m, 64); a2.y += __shfl_xor(a2.y, m, 64);
        a2.z += __shfl_xor(a2.z, m, 64); a2.w += __shfl_xor(a2.w, m, 64);
    }

    if (lane < 16) { s1[wave][l4] = a1; s2[wave][l4] = a2; }
    __syncthreads();

    // cross-wave reduce in LDS + direct bag-row store (32 lanes x float4)
    if (tid < 32) {
        const int h = tid >> 4;          // 0: cols [0,64), 1: cols [64,128)
        const int q = tid & 15;
        float4 f = (h == 0) ? s1[0][q] : s2[0][q];
        #pragma unroll
        for (int w = 1; w < NW; w++) {
            float4 p = (h == 0) ? s1[w][q] : s2[w][q];
            f.x += p.x; f.y += p.y; f.z += p.z; f.w += p.w;
        }
        float* orow = ob + (size_t)(V_ - 1) * E_;
        ((float4*)orow)[tid] = f;
    }
}

extern "C" void kernel_launch(void* const* d_in, const int* in_sizes, int n_in,
                              void* d_out, int out_size, void* d_ws, size_t ws_size,
                              hipStream_t stream) {
    const float* W     = (const float*)d_in[0];
    const int*   codes = (const int*)d_in[1];
    const int*   nvis  = (const int*)d_in[2];
    float*       out   = (float*)d_out;
    (void)d_ws; (void)ws_size;

    fused_kernel<<<B_, THREADS, 0, stream>>>(W, codes, nvis, out);
}